// Round 9
// baseline (60.912 us; speedup 1.0000x reference)
//
#include <hip/hip_runtime.h>
#include <hip/hip_bf16.h>
#include <stdint.h>

typedef short bf16x8 __attribute__((ext_vector_type(8)));
typedef float f32x4  __attribute__((ext_vector_type(4)));

__device__ __forceinline__ ushort f2b(float f) {
  __hip_bfloat16 t = __float2bfloat16(f);
  return *reinterpret_cast<ushort*>(&t);
}
__device__ __forceinline__ bf16x8 pack8(float4 a, float4 b) {
  bf16x8 r;
  r[0]=(short)f2b(a.x); r[1]=(short)f2b(a.y); r[2]=(short)f2b(a.z); r[3]=(short)f2b(a.w);
  r[4]=(short)f2b(b.x); r[5]=(short)f2b(b.y); r[6]=(short)f2b(b.z); r[7]=(short)f2b(b.w);
  return r;
}

// ---------------- Phase 0: repack W1 -> bf16 B-fragment blob ----------------
__global__ void repack_W1(const float* __restrict__ W1, int4* __restrict__ blob) {
  const int tid = blockIdx.x * 256 + threadIdx.x;     // 0..4095
  const int l15  = tid & 15;
  const int lg   = (tid >> 4) & 3;
  const int kk   = (tid >> 6) & 3;
  const int nt   = (tid >> 8) & 7;
  const int half = (tid >> 11) & 1;
  const float* wp = W1 + (size_t)(nt * 16 + l15) * 256 + half * 128 + kk * 32 + lg * 8;
  const float4 fa = *(const float4*)wp;
  const float4 fb = *(const float4*)(wp + 4);
  bf16x8 r = pack8(fa, fb);
  blob[tid] = *reinterpret_cast<int4*>(&r);
}

// global -> LDS direct DMA, 16B per lane. LDS dest = wave-uniform base + lane*16.
__device__ __forceinline__ void dma16(const float4* g, void* lds) {
  __builtin_amdgcn_global_load_lds(
      (const __attribute__((address_space(1))) uint32_t*)g,
      (__attribute__((address_space(3))) uint32_t*)lds, 16, 0, 0);
}

// ---------------- Phase 1: u/v -> biased uint8 + per-half scales --------------------------
// global_load_lds staging of f32 h-tiles (16 nodes x 512B), 4 LDS buffers, 2-tile-ahead
// issue, counted vmcnt (never 0 mid-loop), ONE raw s_barrier per iteration.
// Swizzle: linear LDS dest; per-lane GLOBAL source pre-swizzled chunk c -> c ^ (row&7);
// ds_read applies the same XOR. (both-sides-or-neither, G21)
// Per-iter per-wave VMEM issue order: [2 DMA][5 stores] -> steady-state wait for tile T_i
// with younger = stores(5)+DMA(2)+stores(5)+DMA(2) = vmcnt(14); peeled iters use 4, 9.
// Stores are UNCONDITIONAL (clamped to dump row Nn) so counts are wave-uniform.
// Wave w owns out-cols [64w,64w+64): half=w>>1 (u/v), hw=w&1. Byte layout per node:
// byte pos l15*8 + hw*4 + ntl <-> col hw*64 + ntl*16 + l15 (j<4 scale .x, j>=4 .y).
__global__ __launch_bounds__(256, 4) void node_uv(
    const float* __restrict__ h, const int4* __restrict__ blob,
    const float* __restrict__ b1,
    uint8_t* __restrict__ u8, uint8_t* __restrict__ v8,
    float* __restrict__ su, float* __restrict__ sv,   // [Nn+16][2]
    int Nn, int NT, int nb, int niter)
{
  __shared__ uint8_t As[4][8192];       // 4 x (16 rows x 512B f32), 32 KiB

  const int t0   = threadIdx.x;
  const int w    = t0 >> 6;
  const int l    = t0 & 63;
  const int l15  = l & 15;
  const int lg   = l >> 4;
  const int half = w >> 1;
  const int hw   = w & 1;

  bf16x8 bfrag[4][4];
#pragma unroll
  for (int ntl = 0; ntl < 4; ++ntl)
#pragma unroll
    for (int kk = 0; kk < 4; ++kk) {
      int4 x = blob[((half * 8 + hw * 4 + ntl) * 4 + kk) * 64 + l];
      bfrag[ntl][kk] = *reinterpret_cast<bf16x8*>(&x);
    }

  float b1r[4];
#pragma unroll
  for (int ntl = 0; ntl < 4; ++ntl)
    b1r[ntl] = half ? 0.f : b1[hw * 64 + ntl * 16 + l15];

  uint8_t* __restrict__ outp = half ? v8 : u8;
  float*   __restrict__ outs = half ? sv : su;

  const float4* h4 = (const float4*)h;

  // per-lane DMA slot geometry (fixed): slot s = w*128 + k*64 + l
  const int s0 = w * 128 + l,  srow0 = s0 >> 5, sc0 = s0 & 31;
  const int s1 = s0 + 64,      srow1 = s1 >> 5, sc1 = s1 & 31;
  const int coff0 = sc0 ^ (srow0 & 7);      // pre-swizzled source chunk
  const int coff1 = sc1 ^ (srow1 & 7);

#define DMA_TILE(T, bi)                                                     \
  {                                                                         \
    const int tt = (T) < NT ? (T) : NT - 1;                                 \
    int gr0 = tt * 16 + srow0; if (gr0 >= Nn) gr0 = Nn - 1;                 \
    int gr1 = tt * 16 + srow1; if (gr1 >= Nn) gr1 = Nn - 1;                 \
    dma16(h4 + (size_t)gr0 * 32 + coff0, &As[bi][w * 2048]);                \
    dma16(h4 + (size_t)gr1 * 32 + coff1, &As[bi][w * 2048 + 1024]);         \
  }

#define VMBAR(N)                                                            \
  asm volatile("s_waitcnt vmcnt(" #N ")" ::: "memory");                     \
  __builtin_amdgcn_sched_barrier(0);                                        \
  __builtin_amdgcn_s_barrier();                                             \
  __builtin_amdgcn_sched_barrier(0);

#define COMPUTE(bi, TC)                                                     \
  if ((TC) < NT) {                                                          \
    const uint8_t* Ab = &As[bi][0];                                         \
    f32x4 acc[4];                                                           \
    _Pragma("unroll")                                                       \
    for (int ntl = 0; ntl < 4; ++ntl) acc[ntl] = (f32x4){0.f,0.f,0.f,0.f};  \
    _Pragma("unroll")                                                       \
    for (int kk = 0; kk < 4; ++kk) {                                        \
      const int lc  = kk * 8 + lg * 2;                                      \
      const int pc0 = lc ^ (l15 & 7);                                       \
      const int pc1 = (lc + 1) ^ (l15 & 7);                                 \
      const float4 fa = *(const float4*)(Ab + l15 * 512 + pc0 * 16);        \
      const float4 fb = *(const float4*)(Ab + l15 * 512 + pc1 * 16);        \
      const bf16x8 a = pack8(fa, fb);                                       \
      _Pragma("unroll")                                                     \
      for (int ntl = 0; ntl < 4; ++ntl)                                     \
        acc[ntl] = __builtin_amdgcn_mfma_f32_16x16x32_bf16(                 \
            a, bfrag[ntl][kk], acc[ntl], 0, 0, 0);                          \
    }                                                                       \
    const int n0 = (TC) * 16;                                               \
    _Pragma("unroll")                                                       \
    for (int r = 0; r < 4; ++r) {                                           \
      float vals[4];                                                        \
      float m = 1e-30f;                                                     \
      _Pragma("unroll")                                                     \
      for (int ntl = 0; ntl < 4; ++ntl) {                                   \
        const float x = acc[ntl][r] + b1r[ntl];                             \
        vals[ntl] = x;                                                      \
        m = fmaxf(m, fabsf(x));                                             \
      }                                                                     \
      m = fmaxf(m, __shfl_xor(m, 1));                                       \
      m = fmaxf(m, __shfl_xor(m, 2));                                       \
      m = fmaxf(m, __shfl_xor(m, 4));                                       \
      m = fmaxf(m, __shfl_xor(m, 8));                                       \
      const float inv = 127.0f * __builtin_amdgcn_rcpf(m);                  \
      uint32_t pk = 0;                                                      \
      _Pragma("unroll")                                                     \
      for (int j = 0; j < 4; ++j) {                                         \
        const int q = (int)rintf(vals[j] * inv) + 128;                      \
        pk |= (uint32_t)q << (8 * j);                                       \
      }                                                                     \
      const int node = n0 + lg * 4 + r;                                     \
      const int nd   = node < Nn ? node : Nn;   /* dump row, uniform count */\
      *(uint32_t*)(outp + (size_t)nd * 128 + l15 * 8 + hw * 4) = pk;        \
      if (l15 == 0) outs[nd * 2 + hw] = m * (1.0f / 127.0f);                \
    }                                                                       \
  }

  int tc = blockIdx.x;
  DMA_TILE(tc, 0);                 // T_0
  DMA_TILE(tc + nb, 1);            // T_1

  // iter 0: younger-than-T_0 = T_1(2) + T_2(2) = 4
  DMA_TILE(tc + 2 * nb, 2);
  VMBAR(4)
  COMPUTE(0, tc)
  tc += nb;

  // iter 1: younger-than-T_1 = T_2(2) + stores_0(5) + T_3(2) = 9
  DMA_TILE(tc + 2 * nb, 3);
  VMBAR(9)
  COMPUTE(1, tc)
  tc += nb;

  // steady: younger-than-T_i = stores(5) + T(2) + stores(5) + T(2) = 14
  for (int it = 2; it < niter; ++it) {
    DMA_TILE(tc + 2 * nb, (it + 2) & 3);
    VMBAR(14)
    const int bi = it & 3;
    COMPUTE(bi, tc)
    tc += nb;
  }
#undef DMA_TILE
#undef VMBAR
#undef COMPUTE
}

// ---------------- Phase 2: score[e] = w2 . relu(s_u*(qu-128) + s_v*(qv-128)) + b2 ----------
__global__ __launch_bounds__(256) void edge_score_i8(
    const uint8_t* __restrict__ u8, const uint8_t* __restrict__ v8,
    const float* __restrict__ su, const float* __restrict__ sv,  // [Nn+16][2]
    const int* __restrict__ src, const int* __restrict__ dst,
    const float* __restrict__ w2, const float* __restrict__ b2p,
    float* __restrict__ out, int E)
{
  const int t  = threadIdx.x;
  const int l  = t & 63;
  const int q  = l & 15;
  const int lg = l >> 4;

  float w2r[8];
#pragma unroll
  for (int j = 0; j < 8; ++j) w2r[j] = w2[j * 16 + q];
  const float b2 = b2p[0];

  const int gw = blockIdx.x * 4 + (t >> 6);
  const int TW = gridDim.x * 4;
  const float2* su2 = (const float2*)su;
  const float2* sv2 = (const float2*)sv;

  for (int base = gw * 16; base < E; base += TW * 16) {
    int e[4]; bool ok[4];
    uint2 ug[4], vg[4];
    float2 ss[4], sd[4];
#pragma unroll
    for (int i = 0; i < 4; ++i) {
      e[i]  = base + i * 4 + lg;
      ok[i] = e[i] < E;
      const int eS = ok[i] ? e[i] : 0;
      const int s = src[eS];
      const int d = dst[eS];
      ug[i] = *(const uint2*)(u8 + (size_t)s * 128 + q * 8);
      vg[i] = *(const uint2*)(v8 + (size_t)d * 128 + q * 8);
      ss[i] = su2[s];
      sd[i] = sv2[d];
    }
#pragma unroll
    for (int i = 0; i < 4; ++i) {
      const uint32_t ux = ug[i].x, uy = ug[i].y;
      const uint32_t vx = vg[i].x, vy = vg[i].y;
      const float bse0 = -128.0f * (ss[i].x + sd[i].x);
      const float bse1 = -128.0f * (ss[i].y + sd[i].y);
      float acc = 0.f;
#pragma unroll
      for (int j = 0; j < 4; ++j) {
        const float cu = (float)((ux >> (8 * j)) & 0xffu);   // v_cvt_f32_ubyteN
        const float cv = (float)((vx >> (8 * j)) & 0xffu);
        float x = fmaf(cu, ss[i].x, fmaf(cv, sd[i].x, bse0));
        x = fmaxf(x, 0.f);
        acc = fmaf(x, w2r[j], acc);
      }
#pragma unroll
      for (int j = 0; j < 4; ++j) {
        const float cu = (float)((uy >> (8 * j)) & 0xffu);
        const float cv = (float)((vy >> (8 * j)) & 0xffu);
        float x = fmaf(cu, ss[i].y, fmaf(cv, sd[i].y, bse1));
        x = fmaxf(x, 0.f);
        acc = fmaf(x, w2r[4 + j], acc);
      }
      acc += __shfl_xor(acc, 1);
      acc += __shfl_xor(acc, 2);
      acc += __shfl_xor(acc, 4);
      acc += __shfl_xor(acc, 8);
      if (q == 0 && ok[i]) out[e[i]] = acc + b2;
    }
  }
}

extern "C" void kernel_launch(void* const* d_in, const int* in_sizes, int n_in,
                              void* d_out, int out_size, void* d_ws, size_t ws_size,
                              hipStream_t stream) {
  const float* h   = (const float*)d_in[0];
  const int*   src = (const int*)d_in[1];
  const int*   dst = (const int*)d_in[2];
  const float* W1  = (const float*)d_in[3];
  const float* b1  = (const float*)d_in[4];
  const float* w2  = (const float*)d_in[5];
  const float* b2  = (const float*)d_in[6];
  float* out = (float*)d_out;

  const int nh = in_sizes[0];
  const int Nn = nh / 128;
  const int E  = in_sizes[1];

  uint8_t* ws = (uint8_t*)d_ws;
  int4*  blob = (int4*)ws;                                          // 64 KiB
  size_t off  = 65536;
  float* su   = (float*)(ws + off);  off += (size_t)(Nn + 16) * 8;
  off = (off + 511) & ~(size_t)511;
  float* sv   = (float*)(ws + off);  off += (size_t)(Nn + 16) * 8;
  off = (off + 511) & ~(size_t)511;
  uint8_t* u8 = ws + off;            off += (size_t)(Nn + 16) * 128;
  uint8_t* v8 = ws + off;

  hipLaunchKernelGGL(repack_W1, dim3(16), dim3(256), 0, stream, W1, blob);

  const int NT      = (Nn + 15) / 16;
  const int nblocks = 1024;                    // 4 blocks/CU resident (persistent)
  const int niter   = (NT + nblocks - 1) / nblocks;
  hipLaunchKernelGGL(node_uv, dim3(nblocks), dim3(256), 0, stream,
                     h, blob, b1, u8, v8, su, sv, Nn, NT, nblocks, niter);

  hipLaunchKernelGGL(edge_score_i8, dim3(3072), dim3(256), 0, stream,
                     u8, v8, su, sv, src, dst, w2, b2, out, E);
}